// Round 4
// baseline (16.817 us; speedup 1.0000x reference)
//
#include <hip/hip_runtime.h>
#include <math.h>

// Graphene tight-binding band energies, closed form.
// Per k-point: p = a_lat*kx/2, b = a_lat*ky/(2*sqrt(3)).
// All 9 lattice phases reduce to functions of cos(p), cos(b), sin(b):
//   f_re = -t * (2 cp cb + 2 cb^2 - 1)
//   f_im = -t * (2 sb (cp - cb))
//   e    = -2 t' * (2 cp^2 - 1 + 2 cp (4 cb^3 - 3 cb))
//   out  = (e -/+ sqrt(m^2 + f_re^2 + f_im^2)) * EV_TO_J   [ascending]
//
// Memory-bound (67 MB traffic; in+out fit in 256 MiB L3 across graph
// replays). Grid capped at 2048 blocks, grid-stride with 4-way ILP.
// R3->R4 isolated change: REGULAR (cached, write-back) stores instead of
// nontemporal — let L3 absorb the output stream across replays instead of
// forcing synchronous HBM writes inside the timed region.

typedef float f32x4 __attribute__((ext_vector_type(4)));

namespace {
constexpr double A_LAT_D = 2.46e-10;
constexpr float C_P  = (float)(A_LAT_D * 0.5);                           // a/2
constexpr float C_B  = (float)(A_LAT_D / (2.0 * 1.7320508075688772935)); // a/(2*sqrt3)
constexpr float T_EV  = 2.8f;
constexpr float TP_EV = 0.1f;
constexpr float M_EV  = 0.05f;
constexpr float EVJ   = 1.602176634e-19f;
}

__device__ __forceinline__ void graphene_point(float kx, float ky,
                                               float& lo, float& hi) {
    float p = kx * C_P;
    float b = ky * C_B;
    float cp = __cosf(p);
    float cb = __cosf(b);
    float sb = __sinf(b);
    float cb2 = cb * cb;
    float c3b = cb * (4.0f * cb2 - 3.0f);          // cos(3b)
    float fre = -T_EV * (2.0f * cp * cb + 2.0f * cb2 - 1.0f);
    float fim = -T_EV * (2.0f * sb * (cp - cb));
    float e   = -2.0f * TP_EV * (2.0f * cp * cp - 1.0f + 2.0f * cp * c3b);
    float r   = sqrtf(M_EV * M_EV + fre * fre + fim * fim);
    lo = (e - r) * EVJ;
    hi = (e + r) * EVJ;
}

__device__ __forceinline__ f32x4 graphene_pair(f32x4 kv) {
    f32x4 o;
    float ox, oy, oz, ow;
    graphene_point(kv.x, kv.y, ox, oy);
    graphene_point(kv.z, kv.w, oz, ow);
    o.x = ox; o.y = oy; o.z = oz; o.w = ow;
    return o;
}

__global__ __launch_bounds__(256)
void graphene_kernel(const f32x4* __restrict__ k4, f32x4* __restrict__ out4, int n4) {
    int tid    = blockIdx.x * blockDim.x + threadIdx.x;
    int stride = gridDim.x * blockDim.x;

    int i = tid;
    // main loop: 4 independent loads in flight per thread
    for (; i + 3 * stride < n4; i += 4 * stride) {
        f32x4 a = k4[i];
        f32x4 b = k4[i + stride];
        f32x4 c = k4[i + 2 * stride];
        f32x4 d = k4[i + 3 * stride];
        out4[i]              = graphene_pair(a);
        out4[i + stride]     = graphene_pair(b);
        out4[i + 2 * stride] = graphene_pair(c);
        out4[i + 3 * stride] = graphene_pair(d);
    }
    // tail
    for (; i < n4; i += stride) {
        out4[i] = graphene_pair(k4[i]);
    }
}

extern "C" void kernel_launch(void* const* d_in, const int* in_sizes, int n_in,
                              void* d_out, int out_size, void* d_ws, size_t ws_size,
                              hipStream_t stream) {
    const f32x4* k4 = (const f32x4*)d_in[0];
    f32x4* out4 = (f32x4*)d_out;
    int n_floats = in_sizes[0];          // 2 * N_K
    int n4 = n_floats / 4;               // two k-points per f32x4
    int block = 256;
    int grid  = 2048;                    // grid-stride, ~8 blocks/CU
    graphene_kernel<<<grid, block, 0, stream>>>(k4, out4, n4);
}

// Round 5
// 13.175 us; speedup vs baseline: 1.2764x; 1.2764x over previous
//
#include <hip/hip_runtime.h>
#include <math.h>

// Graphene tight-binding band energies, closed form.
// Per k-point: p = a_lat*kx/2, b = a_lat*ky/(2*sqrt(3)).
//   f_re = -t * (2 cp cb + 2 cb^2 - 1)
//   f_im = -t * (2 sb (cp - cb))
//   e    = -2 t' * (2 cp^2 - 1 + 2 cp (4 cb^3 - 3 cb))
//   out  = (e -/+ sqrt(m^2 + f_re^2 + f_im^2)) * EV_TO_J   [ascending]
//
// Memory-bound (67 MB). R4 evidence: L3 is flushed between replays by the
// harness poison-fills -> nontemporal stores win (+1.8us); keep them.
// R4->R5 isolated change: block-CONTIGUOUS addressing (each block owns one
// 16 KB chunk; thread's 4 accesses 4 KB apart) instead of grid-stride
// (8 MB apart) to restore HBM row-buffer locality. ILP=4, grid=2048 kept.

typedef float f32x4 __attribute__((ext_vector_type(4)));

namespace {
constexpr double A_LAT_D = 2.46e-10;
constexpr float C_P  = (float)(A_LAT_D * 0.5);                           // a/2
constexpr float C_B  = (float)(A_LAT_D / (2.0 * 1.7320508075688772935)); // a/(2*sqrt3)
constexpr float T_EV  = 2.8f;
constexpr float TP_EV = 0.1f;
constexpr float M_EV  = 0.05f;
constexpr float EVJ   = 1.602176634e-19f;
}

__device__ __forceinline__ void graphene_point(float kx, float ky,
                                               float& lo, float& hi) {
    float p = kx * C_P;
    float b = ky * C_B;
    float cp = __cosf(p);
    float cb = __cosf(b);
    float sb = __sinf(b);
    float cb2 = cb * cb;
    float c3b = cb * (4.0f * cb2 - 3.0f);          // cos(3b)
    float fre = -T_EV * (2.0f * cp * cb + 2.0f * cb2 - 1.0f);
    float fim = -T_EV * (2.0f * sb * (cp - cb));
    float e   = -2.0f * TP_EV * (2.0f * cp * cp - 1.0f + 2.0f * cp * c3b);
    float r   = sqrtf(M_EV * M_EV + fre * fre + fim * fim);
    lo = (e - r) * EVJ;
    hi = (e + r) * EVJ;
}

__device__ __forceinline__ f32x4 graphene_pair(f32x4 kv) {
    f32x4 o;
    float ox, oy, oz, ow;
    graphene_point(kv.x, kv.y, ox, oy);
    graphene_point(kv.z, kv.w, oz, ow);
    o.x = ox; o.y = oy; o.z = oz; o.w = ow;
    return o;
}

__global__ __launch_bounds__(256)
void graphene_kernel(const f32x4* __restrict__ k4, f32x4* __restrict__ out4, int n4) {
    constexpr int ILP = 4;
    const int bsz  = 256;
    // each block owns a contiguous chunk of ILP*bsz f32x4 (16 KB in / 16 KB out)
    int base = blockIdx.x * (bsz * ILP) + threadIdx.x;

    if (base + 3 * bsz < n4) {
        f32x4 a = k4[base];
        f32x4 b = k4[base + bsz];
        f32x4 c = k4[base + 2 * bsz];
        f32x4 d = k4[base + 3 * bsz];
        f32x4 oa = graphene_pair(a);
        f32x4 ob = graphene_pair(b);
        f32x4 oc = graphene_pair(c);
        f32x4 od = graphene_pair(d);
        __builtin_nontemporal_store(oa, &out4[base]);
        __builtin_nontemporal_store(ob, &out4[base + bsz]);
        __builtin_nontemporal_store(oc, &out4[base + 2 * bsz]);
        __builtin_nontemporal_store(od, &out4[base + 3 * bsz]);
    } else {
        for (int j = 0; j < ILP; ++j) {
            int i = base + j * bsz;
            if (i < n4)
                __builtin_nontemporal_store(graphene_pair(k4[i]), &out4[i]);
        }
    }
}

extern "C" void kernel_launch(void* const* d_in, const int* in_sizes, int n_in,
                              void* d_out, int out_size, void* d_ws, size_t ws_size,
                              hipStream_t stream) {
    const f32x4* k4 = (const f32x4*)d_in[0];
    f32x4* out4 = (f32x4*)d_out;
    int n_floats = in_sizes[0];          // 2 * N_K
    int n4 = n_floats / 4;               // two k-points per f32x4
    constexpr int ILP = 4;
    int block = 256;
    int grid  = (n4 + block * ILP - 1) / (block * ILP);   // 2048 for N_K=4.2M
    graphene_kernel<<<grid, block, 0, stream>>>(k4, out4, n4);
}